// Round 5
// baseline (312.802 us; speedup 1.0000x reference)
//
#include <hip/hip_runtime.h>

// B=4, T=4096, E=204, H=64, fp32 in/out. Causal single-head attention.
#define TSEQ   4096
#define NB     4
#define EMB    204
#define HD     64
#define WK     224    // padded K dim for projection (204 -> 7*32)
#define XSTR   232    // x LDS row stride (shorts)
#define KTILE  64     // keys per flash tile

typedef __attribute__((ext_vector_type(8))) short bf16x8;
typedef __attribute__((ext_vector_type(4))) float f32x4;
typedef __attribute__((ext_vector_type(16))) float f32x16;
typedef __attribute__((ext_vector_type(4))) unsigned u32x4;

__device__ __forceinline__ short f2bf(float f) {
    unsigned u = __float_as_uint(f);
    return (short)((u + 0x7fffu + ((u >> 16) & 1u)) >> 16);  // RNE
}

// ---------------------------------------------------------------------------
// Prep: W transpose->bf16 (Wt [3][64][224]) + zero the accumulator region.
// ---------------------------------------------------------------------------
__global__ __launch_bounds__(256) void prep_zero_kernel(
    const float* __restrict__ Wq,
    const float* __restrict__ Wk,
    const float* __restrict__ Wv,
    short* __restrict__ Wt,
    float* __restrict__ zacc)     // outacc+lacc, 1064960 floats
{
    int f = blockIdx.x * 256 + threadIdx.x;
    if (f < 3 * HD * WK) {
        int e   = f % WK;
        int h   = (f / WK) % HD;
        int mat = f / (WK * HD);
        const float* W = (mat == 0) ? Wq : (mat == 1) ? Wk : Wv;
        float v = (e < EMB) ? W[e * HD + h] : 0.f;
        Wt[f] = f2bf(v);
    }
    for (int c = blockIdx.x * 256 + threadIdx.x; c < 266240; c += 256 * 256)
        *(float4*)(zacc + c * 4) = make_float4(0.f, 0.f, 0.f, 0.f);
}

// ---------------------------------------------------------------------------
// QKV projection: 1024 blocks x 192 thr (3 waves). Block = 16 x-rows.
// Wave w computes matrix w (28 MFMA). q is PRE-SCALED by log2(e)/sqrt(204)
// so the flash kernel can use native v_exp_f32 (2^x) directly.
// q,k -> [row][64] bf16; v -> vT [b][hd][4096] bf16.
// ---------------------------------------------------------------------------
__global__ __launch_bounds__(192) void qkv_mfma_kernel(
    const float* __restrict__ x,
    const short* __restrict__ Wt,
    short* __restrict__ qg,
    short* __restrict__ kg,
    short* __restrict__ vtg)
{
    __shared__ __align__(16) short xs[16 * XSTR];

    const int t    = threadIdx.x;
    const int lane = t & 63;
    const int w    = t >> 6;          // 0..2 = matrix id
    const int l15  = lane & 15;
    const int quad = lane >> 4;
    const long long rowb = (long long)blockIdx.x * 16;

    for (int c = t; c < 816; c += 192) {
        int r = c / 51, c4 = c % 51;
        float4 xv = *(const float4*)(x + (rowb + r) * EMB + c4 * 4);
        unsigned p0 = (unsigned)(unsigned short)f2bf(xv.x)
                    | ((unsigned)(unsigned short)f2bf(xv.y) << 16);
        unsigned p1 = (unsigned)(unsigned short)f2bf(xv.z)
                    | ((unsigned)(unsigned short)f2bf(xv.w) << 16);
        uint2 pk; pk.x = p0; pk.y = p1;
        *(uint2*)(&xs[r * XSTR + c4 * 4]) = pk;
    }
    for (int c = t; c < 16 * 28; c += 192) {       // zero pad cols 204..231
        int r = c / 28, cc = c % 28;
        xs[r * XSTR + EMB + cc] = 0;
    }
    __syncthreads();

    f32x4 acc[4];
#pragma unroll
    for (int nt = 0; nt < 4; ++nt) acc[nt] = (f32x4){0.f, 0.f, 0.f, 0.f};

    const short* Wb = Wt + (size_t)w * HD * WK;
#pragma unroll
    for (int ks = 0; ks < 7; ++ks) {
        bf16x8 af = *(const bf16x8*)(&xs[l15 * XSTR + ks * 32 + quad * 8]);
#pragma unroll
        for (int nt = 0; nt < 4; ++nt) {
            bf16x8 bfr = *(const bf16x8*)(Wb + (size_t)(nt * 16 + l15) * WK
                                          + ks * 32 + quad * 8);
            acc[nt] = __builtin_amdgcn_mfma_f32_16x16x32_bf16(af, bfr, acc[nt], 0, 0, 0);
        }
    }

    // scale = log2(e) / sqrt(204), folded into q (flash uses exp2)
    const float scale = 0.101008857f;
    if (w == 0) {
#pragma unroll
        for (int r = 0; r < 4; ++r) {
            long long grow = rowb + quad * 4 + r;
#pragma unroll
            for (int nt = 0; nt < 4; ++nt)
                qg[grow * HD + nt * 16 + l15] = f2bf(acc[nt][r] * scale);
        }
    } else if (w == 1) {
#pragma unroll
        for (int r = 0; r < 4; ++r) {
            long long grow = rowb + quad * 4 + r;
#pragma unroll
            for (int nt = 0; nt < 4; ++nt)
                kg[grow * HD + nt * 16 + l15] = f2bf(acc[nt][r]);
        }
    } else {
#pragma unroll
        for (int r = 0; r < 4; ++r) {
            long long grow = rowb + quad * 4 + r;
            int bb = (int)(grow >> 12);
            int tt = (int)(grow & 4095);
#pragma unroll
            for (int nt = 0; nt < 4; ++nt)
                vtg[((long long)bb * HD + nt * 16 + l15) * TSEQ + tt] = f2bf(acc[nt][r]);
        }
    }
}

// ---------------------------------------------------------------------------
// Flash attention v4: swapped-operand 32x32x16 MFMA + in-register softmax.
// Block = 128 q-rows; 4 waves, each owns 32 q-rows x full 64-key tile.
//
// S^T = mfma32(K, Q): lane (l31,hi) holds S[q=l31][key=32kg+(r&3)+8(r>>2)+4hi]
// (C layout col=lane&31, row=(reg&3)+8*(reg>>2)+4*(lane>>5), m74-verified).
// Softmax lane-local: 32 v_exp_f32 (q pre-scaled by log2e), pairwise
// v_cvt_pk_bf16_f32, v_permlane32_swap_b32 redistributes P^T straight into
// PV B-fragments (k = hi*8+j). NO P LDS at all.
// O^T = mfma32(V^T, P^T); epilogue: atomic add (split-K merge as before).
//
// K/V double-buffered via async global_load_lds (linear LDS dest, per-lane
// XOR-swizzled global source chunk' = chunk ^ (row&7)); read side applies
// the same XOR -> bank-conflict-free ds_read_b128 (m214-verified pattern).
// One __syncthreads per tile; STAGE(next) issued before compute(cur).
// Stream-K: qt3 (128-row tile) has nt = 2qt3+2 64-key tiles split into
// s = (qt3+2)>>1 chunks of <=4 -> 272 blocks/batch, 1088 total (~4.25/CU).
// LDS 32 KB -> 4 blocks/CU.
// ---------------------------------------------------------------------------
__global__ __launch_bounds__(256, 4) void flash_mfma_kernel(
    const short* __restrict__ qg,    // bf16 [NB*T][64], pre-scaled
    const short* __restrict__ kg,    // bf16 [NB*T][64]
    const short* __restrict__ vtg,   // bf16 [NB][64][T]
    float* __restrict__ outacc,      // fp32 [NB*T][64], zeroed
    float* __restrict__ lacc)        // fp32 [NB*T], zeroed
{
    __shared__ __align__(16) short Ks[2][KTILE * HD];   // 2 x 8 KB, linear
    __shared__ __align__(16) short Vt[2][HD * KTILE];   // 2 x 8 KB, linear

    const int t    = threadIdx.x;
    const int lane = t & 63;
    const int w    = t >> 6;
    const int l31  = lane & 31;
    const int hi   = lane >> 5;
    const int wq   = w * 32;              // wave's q-row offset in block

    const int b = blockIdx.y;
    const int p = 271 - (int)blockIdx.x;  // biggest qt3 dispatched first

    // Decode p -> (qt3, split): s(qt3) = (qt3+2)>>1, prefix-sum walk.
    int qt3 = 0, base = 0;
    for (;; ++qt3) {
        int sg = (qt3 + 2) >> 1;
        if (p < base + sg) break;
        base += sg;
    }
    const int s      = (qt3 + 2) >> 1;
    const int split  = p - base;
    const int ntiles = 2 * qt3 + 2;
    const int chunk  = (ntiles + s - 1) / s;
    const int kt0    = split * chunk;
    const int kt1    = min(ntiles, kt0 + chunk);

    const int qbase = qt3 * 128;
    const long long rowb = (long long)b * TSEQ;
    const int qA = qbase + wq + l31;      // this lane's q row (within batch)

    // Q B-fragments (pre-scaled): aq[c] = qg[qA][c*16 + hi*8 .. +7]
    bf16x8 aq[4];
#pragma unroll
    for (int c = 0; c < 4; ++c)
        aq[c] = *(const bf16x8*)(qg + (rowb + qA) * HD + c * 16 + hi * 8);

    f32x16 Oacc[2];
#pragma unroll
    for (int hg = 0; hg < 2; ++hg)
#pragma unroll
        for (int r = 0; r < 16; ++r) Oacc[hg][r] = 0.f;
    float lsum = 0.f;

    // Async stage of tile KT into buffer BUF. Each wave issues 2 K + 2 V
    // global_load_lds (1 KB each: 8 rows x 128 B). LDS dest linear; global
    // src chunk = lds_chunk ^ (row&7)  (both tiles are 64 rows x 8 chunks).
#define STAGE(BUF, KT) do {                                                   \
        const int k0s = (KT) * KTILE;                                         \
        _Pragma("unroll")                                                     \
        for (int j = 0; j < 2; ++j) {                                         \
            const int rr = (w * 2 + j) * 8 + (lane >> 3);                     \
            const int cc = (lane & 7) ^ (rr & 7);                             \
            const short* srcK = kg + (rowb + k0s + rr) * HD + cc * 8;         \
            __builtin_amdgcn_global_load_lds(                                 \
                (const __attribute__((address_space(1))) void*)srcK,          \
                (__attribute__((address_space(3))) void*)&Ks[BUF][(w * 2 + j) * 512], \
                16, 0, 0);                                                    \
            const short* srcV = vtg + ((long long)b * HD + rr) * TSEQ + k0s + cc * 8; \
            __builtin_amdgcn_global_load_lds(                                 \
                (const __attribute__((address_space(1))) void*)srcV,          \
                (__attribute__((address_space(3))) void*)&Vt[BUF][(w * 2 + j) * 512], \
                16, 0, 0);                                                    \
        }                                                                     \
    } while (0)

    int cur = 0;
    STAGE(0, kt0);
    __syncthreads();   // drain staging (vmcnt) + sync

    for (int kt = kt0; kt < kt1; ++kt) {
        const int k0 = kt * KTILE;
        if (kt + 1 < kt1) STAGE(cur ^ 1, kt + 1);   // async prefetch next

        const short* ksb = Ks[cur];
        const short* vsb = Vt[cur];
        const bool act  = (k0 <= qbase + wq + 31);  // wave has allowed keys
        const bool full = (k0 + 63 <= qbase + wq);  // no masking needed

        if (act) {
            // ---- S^T = K Q^T, then in-register softmax -> packed P^T ----
            unsigned cd[2][8];
#pragma unroll
            for (int kg2 = 0; kg2 < 2; ++kg2) {
                f32x16 S;
#pragma unroll
                for (int r = 0; r < 16; ++r) S[r] = 0.f;
#pragma unroll
                for (int c = 0; c < 4; ++c) {
                    bf16x8 kf = *(const bf16x8*)(ksb + (kg2 * 32 + l31) * HD
                                   + (((2 * c + hi) ^ (l31 & 7)) * 8));
                    S = __builtin_amdgcn_mfma_f32_32x32x16_bf16(kf, aq[c], S, 0, 0, 0);
                }
                const int jb = k0 + kg2 * 32 + 4 * hi;   // key base for this lane
#pragma unroll
                for (int g = 0; g < 8; ++g) {
                    float e0 = __builtin_amdgcn_exp2f(S[2 * g]);
                    float e1 = __builtin_amdgcn_exp2f(S[2 * g + 1]);
                    if (!full) {
                        const int j0 = jb + 8 * (g >> 1) + 2 * (g & 1);
                        if (j0     > qA) e0 = 0.f;
                        if (j0 + 1 > qA) e1 = 0.f;
                    }
                    lsum += e0 + e1;
                    asm("v_cvt_pk_bf16_f32 %0, %1, %2"
                        : "=v"(cd[kg2][g]) : "v"(e0), "v"(e1));
                }
            }

            // ---- O^T += V^T P^T : permlane32_swap builds P^T B-frags ----
#pragma unroll
            for (int kc = 0; kc < 4; ++kc) {
                unsigned u0 = cd[kc >> 1][4 * (kc & 1) + 0];
                unsigned u1 = cd[kc >> 1][4 * (kc & 1) + 1];
                unsigned u2 = cd[kc >> 1][4 * (kc & 1) + 2];
                unsigned u3 = cd[kc >> 1][4 * (kc & 1) + 3];
                asm("v_permlane32_swap_b32 %0, %1" : "+v"(u0), "+v"(u2));
                asm("v_permlane32_swap_b32 %0, %1" : "+v"(u1), "+v"(u3));
                u32x4 pk = {u0, u1, u2, u3};
                bf16x8 pb = __builtin_bit_cast(bf16x8, pk);
#pragma unroll
                for (int hg = 0; hg < 2; ++hg) {
                    bf16x8 vf = *(const bf16x8*)(vsb + (hg * 32 + l31) * HD
                                   + (((2 * kc + hi) ^ (l31 & 7)) * 8));
                    Oacc[hg] = __builtin_amdgcn_mfma_f32_32x32x16_bf16(vf, pb, Oacc[hg], 0, 0, 0);
                }
            }
        }

        __syncthreads();   // staging of next tile complete; all reads done
        cur ^= 1;
    }

    // l: combine the two 32-key halves (lanes l, l^32), then atomic flush.
    lsum += __shfl_xor(lsum, 32, 64);

    float* oa = outacc + (rowb + qA) * HD;
#pragma unroll
    for (int hg = 0; hg < 2; ++hg)
#pragma unroll
        for (int r = 0; r < 16; ++r)
            atomicAdd(&oa[hg * 32 + 4 * hi + (r & 3) + 8 * (r >> 2)], Oacc[hg][r]);
    if (hi == 0)
        atomicAdd(&lacc[rowb + qA], lsum);
#undef STAGE
}

// ---------------------------------------------------------------------------
// Finalize: out = outacc / lacc. 1024 blocks x 256 thr, 16 rows/block.
// ---------------------------------------------------------------------------
__global__ __launch_bounds__(256) void finalize_kernel(
    const float* __restrict__ outacc,
    const float* __restrict__ lacc,
    float* __restrict__ out)
{
    int row = blockIdx.x * 16 + (threadIdx.x >> 4);
    int c4  = (threadIdx.x & 15) * 4;
    float inv = 1.0f / lacc[row];
    float4 v = *(const float4*)(outacc + (size_t)row * HD + c4);
    v.x *= inv; v.y *= inv; v.z *= inv; v.w *= inv;
    *(float4*)(out + (size_t)row * HD + c4) = v;
}

// ---------------------------------------------------------------------------
extern "C" void kernel_launch(void* const* d_in, const int* in_sizes, int n_in,
                              void* d_out, int out_size, void* d_ws, size_t ws_size,
                              hipStream_t stream)
{
    const float* x  = (const float*)d_in[0];
    const float* Wq = (const float*)d_in[1];
    const float* Wk = (const float*)d_in[2];
    const float* Wv = (const float*)d_in[3];

    const size_t nrows = (size_t)NB * TSEQ;
    short* qg  = (short*)d_ws;                 // bf16 [nrows][64]   2 MB
    short* kg  = qg + nrows * HD;              // bf16 [nrows][64]   2 MB
    short* vtg = kg + nrows * HD;              // bf16 [NB][64][T]   2 MB
    short* Wt  = vtg + nrows * HD;             // bf16 [3][64][224]  84 KB
    float* outacc = (float*)(Wt + 3 * HD * WK);// fp32 [nrows][64]   4 MB
    float* lacc   = outacc + nrows * HD;       // fp32 [nrows]       64 KB
    float* outp = (float*)d_out;

    prep_zero_kernel<<<dim3(256), dim3(256), 0, stream>>>(Wq, Wk, Wv, Wt, outacc);
    qkv_mfma_kernel<<<dim3(1024), dim3(192), 0, stream>>>(x, Wt, qg, kg, vtg);
    flash_mfma_kernel<<<dim3(272, NB), dim3(256), 0, stream>>>(qg, kg, vtg, outacc, lacc);
    finalize_kernel<<<dim3(1024), dim3(256), 0, stream>>>(outacc, lacc, outp);
}

// Round 6
// 109.894 us; speedup vs baseline: 2.8464x; 2.8464x over previous
//
#include <hip/hip_runtime.h>

// B=4, T=4096, E=204, H=64, fp32 in/out. Causal single-head attention.
#define TSEQ   4096
#define NB     4
#define EMB    204
#define HD     64
#define WK     224    // padded K dim for projection (204 -> 7*32)
#define XSTR   232    // x LDS row stride (shorts)
#define KTILE  64     // keys per flash tile

typedef __attribute__((ext_vector_type(8))) short bf16x8;
typedef __attribute__((ext_vector_type(4))) float f32x4;
typedef __attribute__((ext_vector_type(16))) float f32x16;
typedef __attribute__((ext_vector_type(4))) unsigned u32x4;

__device__ __forceinline__ short f2bf(float f) {
    unsigned u = __float_as_uint(f);
    return (short)((u + 0x7fffu + ((u >> 16) & 1u)) >> 16);  // RNE
}

// ---------------------------------------------------------------------------
// Prep: W transpose->bf16 (Wt [3][64][224]). No accumulator zeroing needed:
// the slot-merge path writes every segment unconditionally.
// ---------------------------------------------------------------------------
__global__ __launch_bounds__(256) void prep_kernel(
    const float* __restrict__ Wq,
    const float* __restrict__ Wk,
    const float* __restrict__ Wv,
    short* __restrict__ Wt)
{
    int f = blockIdx.x * 256 + threadIdx.x;
    if (f < 3 * HD * WK) {
        int e   = f % WK;
        int h   = (f / WK) % HD;
        int mat = f / (WK * HD);
        const float* W = (mat == 0) ? Wq : (mat == 1) ? Wk : Wv;
        float v = (e < EMB) ? W[e * HD + h] : 0.f;
        Wt[f] = f2bf(v);
    }
}

// ---------------------------------------------------------------------------
// QKV projection: 1024 blocks x 192 thr (3 waves). Block = 16 x-rows.
// Wave w computes matrix w (28 MFMA). q is PRE-SCALED by log2(e)/sqrt(204)
// so the flash kernel can use native v_exp_f32 (2^x) directly.
// q,k -> [row][64] bf16; v -> vT [b][hd][4096] bf16.
// ---------------------------------------------------------------------------
__global__ __launch_bounds__(192) void qkv_mfma_kernel(
    const float* __restrict__ x,
    const short* __restrict__ Wt,
    short* __restrict__ qg,
    short* __restrict__ kg,
    short* __restrict__ vtg)
{
    __shared__ __align__(16) short xs[16 * XSTR];

    const int t    = threadIdx.x;
    const int lane = t & 63;
    const int w    = t >> 6;          // 0..2 = matrix id
    const int l15  = lane & 15;
    const int quad = lane >> 4;
    const long long rowb = (long long)blockIdx.x * 16;

    for (int c = t; c < 816; c += 192) {
        int r = c / 51, c4 = c % 51;
        float4 xv = *(const float4*)(x + (rowb + r) * EMB + c4 * 4);
        unsigned p0 = (unsigned)(unsigned short)f2bf(xv.x)
                    | ((unsigned)(unsigned short)f2bf(xv.y) << 16);
        unsigned p1 = (unsigned)(unsigned short)f2bf(xv.z)
                    | ((unsigned)(unsigned short)f2bf(xv.w) << 16);
        uint2 pk; pk.x = p0; pk.y = p1;
        *(uint2*)(&xs[r * XSTR + c4 * 4]) = pk;
    }
    for (int c = t; c < 16 * 28; c += 192) {       // zero pad cols 204..231
        int r = c / 28, cc = c % 28;
        xs[r * XSTR + EMB + cc] = 0;
    }
    __syncthreads();

    f32x4 acc[4];
#pragma unroll
    for (int nt = 0; nt < 4; ++nt) acc[nt] = (f32x4){0.f, 0.f, 0.f, 0.f};

    const short* Wb = Wt + (size_t)w * HD * WK;
#pragma unroll
    for (int ks = 0; ks < 7; ++ks) {
        bf16x8 af = *(const bf16x8*)(&xs[l15 * XSTR + ks * 32 + quad * 8]);
#pragma unroll
        for (int nt = 0; nt < 4; ++nt) {
            bf16x8 bfr = *(const bf16x8*)(Wb + (size_t)(nt * 16 + l15) * WK
                                          + ks * 32 + quad * 8);
            acc[nt] = __builtin_amdgcn_mfma_f32_16x16x32_bf16(af, bfr, acc[nt], 0, 0, 0);
        }
    }

    // scale = log2(e) / sqrt(204), folded into q (flash uses exp2)
    const float scale = 0.101008857f;
    if (w == 0) {
#pragma unroll
        for (int r = 0; r < 4; ++r) {
            long long grow = rowb + quad * 4 + r;
#pragma unroll
            for (int nt = 0; nt < 4; ++nt)
                qg[grow * HD + nt * 16 + l15] = f2bf(acc[nt][r] * scale);
        }
    } else if (w == 1) {
#pragma unroll
        for (int r = 0; r < 4; ++r) {
            long long grow = rowb + quad * 4 + r;
#pragma unroll
            for (int nt = 0; nt < 4; ++nt)
                kg[grow * HD + nt * 16 + l15] = f2bf(acc[nt][r]);
        }
    } else {
#pragma unroll
        for (int r = 0; r < 4; ++r) {
            long long grow = rowb + quad * 4 + r;
            int bb = (int)(grow >> 12);
            int tt = (int)(grow & 4095);
#pragma unroll
            for (int nt = 0; nt < 4; ++nt)
                vtg[((long long)bb * HD + nt * 16 + l15) * TSEQ + tt] = f2bf(acc[nt][r]);
        }
    }
}

// ---------------------------------------------------------------------------
// Flash attention v5: v4's compute (swapped-operand 32x32x16 MFMA, in-reg
// softmax via exp2 + v_cvt_pk_bf16_f32 + v_permlane32_swap_b32, XOR-swizzled
// K/V staging, 1 barrier/tile) with NO ATOMICS.
//
// Evidence: v1/v4 durations exactly equal hbm_bytes / ~770 GB/s -> the
// atomic-RMW line traffic was the binding constraint (153 MB in v4).
// v5: each split-block streams its partial (O,l) to a private compact
// segment (seg id = stream-K index p), coalesced dwordx4, fragment-linear
// layout: optr[w*2048 + lane*32 + hg*16 + r]. finalize sums s(qt3) segments.
// Every segment is written unconditionally (empty chunks write zeros), so
// no zero-init pass is needed.
//
// Stream-K decode: qt3 (128-row q-tile) has n = 2qt3+2 64-key tiles, split
// into s = min(smax, (qt3+2)>>1) chunks. smax chosen host-side from ws_size.
// ---------------------------------------------------------------------------
__global__ __launch_bounds__(256, 4) void flash_mfma_kernel(
    const short* __restrict__ qg,    // bf16 [NB*T][64], pre-scaled
    const short* __restrict__ kg,    // bf16 [NB*T][64]
    const short* __restrict__ vtg,   // bf16 [NB][64][T]
    float* __restrict__ oparts,      // fp32 [NB][NSEG][8192]
    float* __restrict__ lparts,      // fp32 [NB][NSEG][128]
    int NSEGk, int smax)
{
    __shared__ __align__(16) short Ks[2][KTILE * HD];   // 2 x 8 KB, linear
    __shared__ __align__(16) short Vt[2][HD * KTILE];   // 2 x 8 KB, linear

    const int t    = threadIdx.x;
    const int lane = t & 63;
    const int w    = t >> 6;
    const int l31  = lane & 31;
    const int hi   = lane >> 5;
    const int wq   = w * 32;              // wave's q-row offset in block

    const int b = blockIdx.y;
    const int p = NSEGk - 1 - (int)blockIdx.x;  // biggest qt3 dispatched first

    // Decode p -> (qt3, split): s(qt3) = min(smax,(qt3+2)>>1), prefix walk.
    int qt3 = 0, base = 0;
    for (;; ++qt3) {
        int sg = (qt3 + 2) >> 1;
        if (sg > smax) sg = smax;
        if (p < base + sg) break;
        base += sg;
    }
    int s = (qt3 + 2) >> 1;
    if (s > smax) s = smax;
    const int split  = p - base;
    const int ntiles = 2 * qt3 + 2;
    const int chunk  = (ntiles + s - 1) / s;
    const int kt0    = split * chunk;               // may be >= kt1 (empty)
    const int kt1    = min(ntiles, kt0 + chunk);

    const int qbase = qt3 * 128;
    const long long rowb = (long long)b * TSEQ;
    const int qA = qbase + wq + l31;      // this lane's q row (within batch)

    // Q B-fragments (pre-scaled): aq[c] = qg[qA][c*16 + hi*8 .. +7]
    bf16x8 aq[4];
#pragma unroll
    for (int c = 0; c < 4; ++c)
        aq[c] = *(const bf16x8*)(qg + (rowb + qA) * HD + c * 16 + hi * 8);

    f32x16 Oacc[2];
#pragma unroll
    for (int hg = 0; hg < 2; ++hg)
#pragma unroll
        for (int r = 0; r < 16; ++r) Oacc[hg][r] = 0.f;
    float lsum = 0.f;

    // Async stage of tile KT into buffer BUF. Each wave issues 2 K + 2 V
    // global_load_lds (1 KB each: 8 rows x 128 B). LDS dest linear; global
    // src chunk = lds_chunk ^ (row&7)  (both tiles are 64 rows x 8 chunks).
    // Max staged row: kt0 <= (s-1)*ceil(n/s) <= 56 -> k0s+63 <= 3647 < 4096.
#define STAGE(BUF, KT) do {                                                   \
        const int k0s = (KT) * KTILE;                                         \
        _Pragma("unroll")                                                     \
        for (int j = 0; j < 2; ++j) {                                         \
            const int rr = (w * 2 + j) * 8 + (lane >> 3);                     \
            const int cc = (lane & 7) ^ (rr & 7);                             \
            const short* srcK = kg + (rowb + k0s + rr) * HD + cc * 8;         \
            __builtin_amdgcn_global_load_lds(                                 \
                (const __attribute__((address_space(1))) void*)srcK,          \
                (__attribute__((address_space(3))) void*)&Ks[BUF][(w * 2 + j) * 512], \
                16, 0, 0);                                                    \
            const short* srcV = vtg + ((long long)b * HD + rr) * TSEQ + k0s + cc * 8; \
            __builtin_amdgcn_global_load_lds(                                 \
                (const __attribute__((address_space(1))) void*)srcV,          \
                (__attribute__((address_space(3))) void*)&Vt[BUF][(w * 2 + j) * 512], \
                16, 0, 0);                                                    \
        }                                                                     \
    } while (0)

    int cur = 0;
    STAGE(0, kt0);
    __syncthreads();   // drain staging (vmcnt) + sync

    for (int kt = kt0; kt < kt1; ++kt) {
        const int k0 = kt * KTILE;
        if (kt + 1 < kt1) STAGE(cur ^ 1, kt + 1);   // async prefetch next

        const short* ksb = Ks[cur];
        const short* vsb = Vt[cur];
        const bool act  = (k0 <= qbase + wq + 31);  // wave has allowed keys
        const bool full = (k0 + 63 <= qbase + wq);  // no masking needed

        if (act) {
            // ---- S^T = K Q^T, then in-register softmax -> packed P^T ----
            unsigned cd[2][8];
#pragma unroll
            for (int kg2 = 0; kg2 < 2; ++kg2) {
                f32x16 S;
#pragma unroll
                for (int r = 0; r < 16; ++r) S[r] = 0.f;
#pragma unroll
                for (int c = 0; c < 4; ++c) {
                    bf16x8 kf = *(const bf16x8*)(ksb + (kg2 * 32 + l31) * HD
                                   + (((2 * c + hi) ^ (l31 & 7)) * 8));
                    S = __builtin_amdgcn_mfma_f32_32x32x16_bf16(kf, aq[c], S, 0, 0, 0);
                }
                const int jb = k0 + kg2 * 32 + 4 * hi;   // key base for this lane
#pragma unroll
                for (int g = 0; g < 8; ++g) {
                    float e0 = __builtin_amdgcn_exp2f(S[2 * g]);
                    float e1 = __builtin_amdgcn_exp2f(S[2 * g + 1]);
                    if (!full) {
                        const int j0 = jb + 8 * (g >> 1) + 2 * (g & 1);
                        if (j0     > qA) e0 = 0.f;
                        if (j0 + 1 > qA) e1 = 0.f;
                    }
                    lsum += e0 + e1;
                    asm("v_cvt_pk_bf16_f32 %0, %1, %2"
                        : "=v"(cd[kg2][g]) : "v"(e0), "v"(e1));
                }
            }

            // ---- O^T += V^T P^T : permlane32_swap builds P^T B-frags ----
#pragma unroll
            for (int kc = 0; kc < 4; ++kc) {
                unsigned u0 = cd[kc >> 1][4 * (kc & 1) + 0];
                unsigned u1 = cd[kc >> 1][4 * (kc & 1) + 1];
                unsigned u2 = cd[kc >> 1][4 * (kc & 1) + 2];
                unsigned u3 = cd[kc >> 1][4 * (kc & 1) + 3];
                asm("v_permlane32_swap_b32 %0, %1" : "+v"(u0), "+v"(u2));
                asm("v_permlane32_swap_b32 %0, %1" : "+v"(u1), "+v"(u3));
                u32x4 pk = {u0, u1, u2, u3};
                bf16x8 pb = __builtin_bit_cast(bf16x8, pk);
#pragma unroll
                for (int hg = 0; hg < 2; ++hg) {
                    bf16x8 vf = *(const bf16x8*)(vsb + (hg * 32 + l31) * HD
                                   + (((2 * kc + hi) ^ (l31 & 7)) * 8));
                    Oacc[hg] = __builtin_amdgcn_mfma_f32_32x32x16_bf16(vf, pb, Oacc[hg], 0, 0, 0);
                }
            }
        }

        __syncthreads();   // staging of next tile complete; all reads done
        cur ^= 1;
    }

    // ---- Epilogue: stream partial (O, l) to this block's private segment.
    // Layout: oparts[b][p][w*2048 + lane*32 + hg*16 + r]  (coalesced x4).
    float* optr = oparts + ((size_t)b * NSEGk + p) * 8192
                + (size_t)w * 2048 + (size_t)lane * 32;
#pragma unroll
    for (int hg = 0; hg < 2; ++hg)
#pragma unroll
        for (int rq = 0; rq < 4; ++rq) {
            float4 v = make_float4(Oacc[hg][4 * rq + 0], Oacc[hg][4 * rq + 1],
                                   Oacc[hg][4 * rq + 2], Oacc[hg][4 * rq + 3]);
            *(float4*)(optr + hg * 16 + rq * 4) = v;
        }

    lsum += __shfl_xor(lsum, 32, 64);
    if (hi == 0)
        lparts[((size_t)b * NSEGk + p) * 128 + w * 32 + l31] = lsum;
#undef STAGE
}

// ---------------------------------------------------------------------------
// Finalize: out[row][col] = sum_s opart / sum_s lpart. 1024 x 256, 16 rows/blk.
// col -> fragment index: hi=(col>>2)&1, hg=col>>5, r=(col&3)+4*((col&31)>>3).
// ---------------------------------------------------------------------------
__global__ __launch_bounds__(256) void finalize_kernel(
    const float* __restrict__ oparts,
    const float* __restrict__ lparts,
    float* __restrict__ out,
    int NSEGk, int smax)
{
    const int row = blockIdx.x * 16 + (threadIdx.x >> 4);
    const int c0  = (threadIdx.x & 15) * 4;
    const int b = row >> 12, rowin = row & 4095;
    const int qt3 = rowin >> 7, w = (rowin >> 5) & 3, l31 = rowin & 31;

    int segbase = 0;
    for (int j = 0; j < qt3; ++j) {
        int sg = (j + 2) >> 1;
        if (sg > smax) sg = smax;
        segbase += sg;
    }
    int s = (qt3 + 2) >> 1;
    if (s > smax) s = smax;

    const int hg = c0 >> 5, hiq = (c0 >> 2) & 1, rq = (c0 & 31) >> 3;
    const int lane = hiq * 32 + l31;

    const float* obase = oparts + ((size_t)b * NSEGk + segbase) * 8192
                       + (size_t)w * 2048 + (size_t)lane * 32 + hg * 16 + rq * 4;
    const float* lbase = lparts + ((size_t)b * NSEGk + segbase) * 128 + w * 32 + l31;

    float4 acc = make_float4(0.f, 0.f, 0.f, 0.f);
    float lsum = 0.f;
    for (int k = 0; k < s; ++k) {
        float4 v = *(const float4*)(obase + (size_t)k * 8192);
        acc.x += v.x; acc.y += v.y; acc.z += v.z; acc.w += v.w;
        lsum += lbase[(size_t)k * 128];
    }
    float inv = 1.0f / lsum;
    acc.x *= inv; acc.y *= inv; acc.z *= inv; acc.w *= inv;
    *(float4*)(out + (size_t)row * HD + c0) = acc;
}

// ---------------------------------------------------------------------------
extern "C" void kernel_launch(void* const* d_in, const int* in_sizes, int n_in,
                              void* d_out, int out_size, void* d_ws, size_t ws_size,
                              hipStream_t stream)
{
    const float* x  = (const float*)d_in[0];
    const float* Wq = (const float*)d_in[1];
    const float* Wk = (const float*)d_in[2];
    const float* Wv = (const float*)d_in[3];

    const size_t nrows = (size_t)NB * TSEQ;

    // Choose split depth from workspace budget (smax=1 needs ~10.3 MB, the
    // footprint already proven to fit in prior rounds).
    const size_t fixed_bytes = 3 * nrows * HD * 2 + (size_t)3 * HD * WK * 2;
    int smax = 1, NSEG = 32;
    const int cands[3] = {8, 4, 2};
    for (int i = 0; i < 3; ++i) {
        int sm = cands[i], ns = 0;
        for (int q = 0; q < 32; ++q) {
            int sg = (q + 2) >> 1;
            if (sg > sm) sg = sm;
            ns += sg;
        }
        size_t need = fixed_bytes + (size_t)NB * ns * (8192 + 128) * 4;
        if (need <= ws_size) { smax = sm; NSEG = ns; break; }
    }

    short* qg  = (short*)d_ws;                 // bf16 [nrows][64]   2 MB
    short* kg  = qg + nrows * HD;              // bf16 [nrows][64]   2 MB
    short* vtg = kg + nrows * HD;              // bf16 [NB][64][T]   2 MB
    short* Wt  = vtg + nrows * HD;             // bf16 [3][64][224]  84 KB
    float* oparts = (float*)(Wt + 3 * HD * WK);// fp32 [NB][NSEG][8192]
    float* lparts = oparts + (size_t)NB * NSEG * 8192; // fp32 [NB][NSEG][128]
    float* outp = (float*)d_out;

    prep_kernel<<<dim3(168), dim3(256), 0, stream>>>(Wq, Wk, Wv, Wt);
    qkv_mfma_kernel<<<dim3(1024), dim3(192), 0, stream>>>(x, Wt, qg, kg, vtg);
    flash_mfma_kernel<<<dim3(NSEG, NB), dim3(256), 0, stream>>>(qg, kg, vtg,
                                                               oparts, lparts,
                                                               NSEG, smax);
    finalize_kernel<<<dim3(1024), dim3(256), 0, stream>>>(oparts, lparts, outp,
                                                          NSEG, smax);
}